// Round 1
// baseline (188.282 us; speedup 1.0000x reference)
//
#include <hip/hip_runtime.h>
#include <math.h>

#define NBINS   129
#define NFFT    256
#define WINL    768
#define TFRAMES 4096
#define OUTL    523640          // 4096*128 - 648
#define SHIFT   648
#define WSEG    26
#define CHUNK   (WSEG * 128)    // 3328 output samples per block
#define NCHUNK  ((OUTL + CHUNK - 1) / CHUNK)   // 158
#define FF      32              // frames staged per block (WSEG + 6)

// LDS: spec 129*32*2*4 = 33024 B (aliased by G 32*256*4 = 32768 B) + lpf 3072 B
__global__ __launch_bounds__(256, 2)
void pfb_fused_kernel(const float* __restrict__ gre, const float* __restrict__ gim,
                      const float* __restrict__ glpf, float* __restrict__ out)
{
    __shared__ float s_buf[NBINS * FF * 2];
    __shared__ float s_lpf[WINL];
    float (*s_re)[FF]  = (float (*)[FF])s_buf;
    float (*s_im)[FF]  = (float (*)[FF])(s_buf + NBINS * FF);
    float (*s_G)[NFFT] = (float (*)[NFFT])s_buf;   // aliases spec after 2nd barrier

    const int q   = blockIdx.x;
    const int bc  = blockIdx.y;
    const int tid = threadIdx.x;
    const int t0  = WSEG * q;
    const size_t specBase = (size_t)bc * NBINS * TFRAMES;

    // ---- phase 0/1: stage lpf + 32 frames of spectrum (coalesced over t) ----
    for (int idx = tid; idx < WINL; idx += 256) s_lpf[idx] = glpf[idx];
    for (int idx = tid; idx < NBINS * FF; idx += 256) {
        const int k = idx >> 5, f = idx & 31;
        const int t = t0 + f;
        float vr = 0.f, vi = 0.f;
        if (t < TFRAMES) {
            const size_t g = specBase + (size_t)k * TFRAMES + (size_t)t;
            vr = gre[g]; vi = gim[g];
        }
        s_re[k][f] = vr; s_im[k][f] = vi;
    }
    __syncthreads();

    // ---- phase 2: DFT. thread = (fg, ng); covers m = ng+64j (j<4), f = 8*fg..+7 ----
    const int ng = tid & 63;
    const int fg = tid >> 6;
    const int f0 = fg * 8;

    float cphi[4], sphi[4], cc[4], ss[4];
    float acc[4][8];
    #pragma unroll
    for (int j = 0; j < 4; ++j) {
        const int m = ng + 64 * j;
        // angle step phi = 2*pi*(m+1)/256 = pi * (m+1)/128, argument exact in f32
        sincospif((float)(m + 1) * (1.0f / 128.0f), &sphi[j], &cphi[j]);
        cc[j] = 1.f; ss[j] = 0.f;
        #pragma unroll
        for (int f = 0; f < 8; ++f) acc[j][f] = 0.f;
    }

    #pragma unroll 2
    for (int k = 1; k <= 127; ++k) {
        const float4 rl = *(const float4*)&s_re[k][f0];
        const float4 rh = *(const float4*)&s_re[k][f0 + 4];
        const float4 il = *(const float4*)&s_im[k][f0];
        const float4 ih = *(const float4*)&s_im[k][f0 + 4];
        #pragma unroll
        for (int j = 0; j < 4; ++j) {
            const float c2 = cc[j] * cphi[j] - ss[j] * sphi[j];  // rot(k*phi)
            const float s2 = ss[j] * cphi[j] + cc[j] * sphi[j];
            cc[j] = c2; ss[j] = s2;
            acc[j][0] += rl.x * c2 + il.x * s2;
            acc[j][1] += rl.y * c2 + il.y * s2;
            acc[j][2] += rl.z * c2 + il.z * s2;
            acc[j][3] += rl.w * c2 + il.w * s2;
            acc[j][4] += rh.x * c2 + ih.x * s2;
            acc[j][5] += rh.y * c2 + ih.y * s2;
            acc[j][6] += rh.z * c2 + ih.z * s2;
            acc[j][7] += rh.w * c2 + ih.w * s2;
        }
    }

    // edge bins k=0, k=128 (imag parts ignored by irfft)
    float r0[8], r128[8];
    #pragma unroll
    for (int f = 0; f < 8; ++f) { r0[f] = s_re[0][f0 + f]; r128[f] = s_re[128][f0 + f]; }
    __syncthreads();   // spec fully consumed; safe to alias with G

    #pragma unroll
    for (int j = 0; j < 4; ++j) {
        const int m = ng + 64 * j;
        const float sgn = (m & 1) ? 1.0f : -1.0f;     // (-1)^(m+1)
        #pragma unroll
        for (int f = 0; f < 8; ++f)
            s_G[f0 + f][m] = (r0[f] + 2.0f * acc[j][f] + sgn * r128[f]) * (1.0f / 256.0f);
    }
    __syncthreads();

    // ---- phase 3: overlap-add + scale + shift ----
    const size_t outBase = (size_t)bc * OUTL;
    const int i0 = q * CHUNK;
    #pragma unroll 1
    for (int r = 0; r < 13; ++r) {
        const int i = i0 + r * 256 + tid;
        if (i < OUTL) {
            const int s = i + SHIFT;
            int tlo = (s - 640) >> 7;  if (tlo < t0) tlo = t0;           // ceil((s-767)/128)
            int thi = s >> 7;
            if (thi > t0 + FF - 1) thi = t0 + FF - 1;
            if (thi > TFRAMES - 1) thi = TFRAMES - 1;
            float sum = 0.f;
            for (int t = tlo; t <= thi; ++t) {
                const int jj = s - (t << 7);          // in [0, 768)
                sum += s_lpf[jj] * s_G[t - t0][jj & 255];
            }
            out[outBase + i] = sum * (-32768.0f);     // FRM_LEN * SCALE
        }
    }
}

extern "C" void kernel_launch(void* const* d_in, const int* in_sizes, int n_in,
                              void* d_out, int out_size, void* d_ws, size_t ws_size,
                              hipStream_t stream)
{
    const float* gre  = (const float*)d_in[0];
    const float* gim  = (const float*)d_in[1];
    const float* glpf = (const float*)d_in[2];
    float* out = (float*)d_out;

    dim3 grid(NCHUNK, 16);   // 158 chunks x (B*C = 16)
    pfb_fused_kernel<<<grid, 256, 0, stream>>>(gre, gim, glpf, out);
}

// Round 2
// 74.642 us; speedup vs baseline: 2.5225x; 2.5225x over previous
//
#include <hip/hip_runtime.h>
#include <math.h>

#define NBINS   129
#define NFFT    256
#define WINL    768
#define TFRAMES 4096
#define OUTL    523640          // 4096*128 - 648
#define SHIFT   648
#define WSEG    26
#define CHUNK   (WSEG * 128)    // 3328 output samples per block
#define NCHUNK  ((OUTL + CHUNK - 1) / CHUNK)   // 158
#define FF      32              // frames staged per block (WSEG + 6)

#define KDIM    288             // 258 real K padded to 9*32
#define KROW    296             // LDS row stride (ushorts): 592B == 20 banks mod 32
#define GROW    260             // s_G row stride (floats): 2-way bank pattern (free)
#define WBYTES  (16 * 9 * 64 * 16)   // 147456 B packed twiddles

typedef __attribute__((ext_vector_type(8))) short bf16x8;   // 8 bf16 = 4 VGPR
typedef __attribute__((ext_vector_type(4))) float f32x4;

static __device__ __forceinline__ ushort f2bf(float x) {
    union { float f; unsigned u; } v; v.f = x;
    unsigned r = v.u + 0x7FFFu + ((v.u >> 16) & 1u);   // RTN-even
    return (ushort)(r >> 16);
}

// ---- pre-kernel: W[m][kappa] packed in mfma A-fragment order ----------------
// frag id = mt*9+ks (mt<16, ks<9); lane supplies row m=mt*16+(lane&15),
// k-run kappa = ks*32 + (lane>>4)*8 + e, e=0..7.  16B per (frag,lane).
__global__ void build_w_kernel(ushort* __restrict__ wp)
{
    const int gid  = blockIdx.x * 256 + threadIdx.x;    // 0..9215
    const int lane = gid & 63;
    const int mtks = gid >> 6;                          // 0..143
    const int ks   = mtks % 9;
    const int mt   = mtks / 9;
    const int m    = mt * 16 + (lane & 15);
    const int kb   = ks * 32 + ((lane >> 4) << 3);

    ushort o[8];
    #pragma unroll
    for (int e = 0; e < 8; ++e) {
        const int kap = kb + e;
        float val = 0.f;
        if (kap < 258) {
            const int k = kap >> 1;
            float s, c;
            sincospif((float)(k * (m + 1)) * (1.0f / 128.0f), &s, &c);
            if (kap & 1)  val = (k >= 1 && k <= 127) ? s * (2.0f / 256.0f) : 0.f;
            else          val = (k == 0 || k == 128) ? c * (1.0f / 256.0f)
                                                     : c * (2.0f / 256.0f);
        }
        o[e] = f2bf(val);
    }
    int4 pk;
    pk.x = o[0] | (o[1] << 16); pk.y = o[2] | (o[3] << 16);
    pk.z = o[4] | (o[5] << 16); pk.w = o[6] | (o[7] << 16);
    ((int4*)wp)[gid] = pk;
}

// ---- main fused kernel: stage -> MFMA DFT -> overlap-add --------------------
__global__ __launch_bounds__(256, 3)
void pfb_mfma_kernel(const float* __restrict__ gre, const float* __restrict__ gim,
                     const float* __restrict__ glpf, const ushort* __restrict__ wp,
                     float* __restrict__ out)
{
    __shared__ float s_buf[FF * GROW];     // 33280 B; aliases bf16 B (18944 B)
    __shared__ float s_lpf[WINL];
    ushort* s_Bu = (ushort*)s_buf;
    float (*s_G)[GROW] = (float (*)[GROW])s_buf;

    const int q   = blockIdx.x;
    const int bc  = blockIdx.y;
    const int tid = threadIdx.x;
    const int t0  = WSEG * q;
    const size_t specBase = (size_t)bc * NBINS * TFRAMES;

    for (int idx = tid; idx < WINL; idx += 256) s_lpf[idx] = glpf[idx];

    // stage spectrum (coalesced over t) as bf16, layout s_B[f][2k | 2k+1]
    for (int idx = tid; idx < NBINS * FF; idx += 256) {
        const int k = idx >> 5, f = idx & 31;
        const int t = t0 + f;
        float vr = 0.f, vi = 0.f;
        if (t < TFRAMES) {
            const size_t g = specBase + (size_t)k * TFRAMES + (size_t)t;
            vr = gre[g]; vi = gim[g];
        }
        s_Bu[f * KROW + 2 * k]     = f2bf(vr);
        s_Bu[f * KROW + 2 * k + 1] = f2bf(vi);
    }
    // zero-pad kappa = 258..295
    for (int idx = tid; idx < FF * (KROW - 258); idx += 256) {
        const int f = idx / (KROW - 258), r = idx - f * (KROW - 258);
        s_Bu[f * KROW + 258 + r] = 0;
    }
    __syncthreads();

    // ---- GEMM: G[256][32] = W[256][288] x B[288][32] ----
    const int lane = tid & 63;
    const int wid  = tid >> 6;
    const int brow = lane & 15;
    const int kgrp = (lane >> 4) << 3;

    bf16x8 bfrag[2][9];
    #pragma unroll
    for (int nt = 0; nt < 2; ++nt)
        #pragma unroll
        for (int ks = 0; ks < 9; ++ks)
            bfrag[nt][ks] = *(const bf16x8*)&s_Bu[(nt * 16 + brow) * KROW + ks * 32 + kgrp];

    f32x4 acc[4][2];
    #pragma unroll
    for (int mi = 0; mi < 4; ++mi)
        #pragma unroll
        for (int nt = 0; nt < 2; ++nt)
            acc[mi][nt] = (f32x4){0.f, 0.f, 0.f, 0.f};

    #pragma unroll 1
    for (int mi = 0; mi < 4; ++mi) {
        const ushort* wbase = wp + ((size_t)((wid * 4 + mi) * 9) * 64 + lane) * 8;
        bf16x8 aw[9];
        #pragma unroll
        for (int ks = 0; ks < 9; ++ks)
            aw[ks] = *(const bf16x8*)(wbase + ks * 512);
        #pragma unroll
        for (int ks = 0; ks < 9; ++ks) {
            acc[mi][0] = __builtin_amdgcn_mfma_f32_16x16x32_bf16(aw[ks], bfrag[0][ks], acc[mi][0], 0, 0, 0);
            acc[mi][1] = __builtin_amdgcn_mfma_f32_16x16x32_bf16(aw[ks], bfrag[1][ks], acc[mi][1], 0, 0, 0);
        }
    }
    __syncthreads();   // B fully consumed; alias with s_G

    // D layout: col(frame) = lane&15, row(m) = (lane>>4)*4 + e  -> float4 store
    #pragma unroll
    for (int mi = 0; mi < 4; ++mi) {
        const int m0 = (wid * 4 + mi) * 16 + ((lane >> 4) << 2);
        #pragma unroll
        for (int nt = 0; nt < 2; ++nt) {
            const int f = nt * 16 + brow;
            *(f32x4*)&s_G[f][m0] = acc[mi][nt];
        }
    }
    __syncthreads();

    // ---- overlap-add + scale + shift ----
    const size_t outBase = (size_t)bc * OUTL;
    const int i0 = q * CHUNK;
    #pragma unroll 1
    for (int r = 0; r < 13; ++r) {
        const int i = i0 + r * 256 + tid;
        if (i < OUTL) {
            const int s = i + SHIFT;
            int tlo = (s - 640) >> 7;  if (tlo < t0) tlo = t0;
            int thi = s >> 7;
            if (thi > t0 + FF - 1) thi = t0 + FF - 1;
            if (thi > TFRAMES - 1) thi = TFRAMES - 1;
            float sum = 0.f;
            for (int t = tlo; t <= thi; ++t) {
                const int jj = s - (t << 7);
                sum += s_lpf[jj] * s_G[t - t0][jj & 255];
            }
            out[outBase + i] = sum * (-32768.0f);
        }
    }
}

// ---- fallback (round-1 f32 path, used only if ws too small) -----------------
__global__ __launch_bounds__(256, 2)
void pfb_fused_kernel(const float* __restrict__ gre, const float* __restrict__ gim,
                      const float* __restrict__ glpf, float* __restrict__ out)
{
    __shared__ float s_buf[NBINS * FF * 2];
    __shared__ float s_lpf[WINL];
    float (*s_re)[FF]  = (float (*)[FF])s_buf;
    float (*s_im)[FF]  = (float (*)[FF])(s_buf + NBINS * FF);
    float (*s_G)[NFFT] = (float (*)[NFFT])s_buf;

    const int q = blockIdx.x, bc = blockIdx.y, tid = threadIdx.x;
    const int t0 = WSEG * q;
    const size_t specBase = (size_t)bc * NBINS * TFRAMES;

    for (int idx = tid; idx < WINL; idx += 256) s_lpf[idx] = glpf[idx];
    for (int idx = tid; idx < NBINS * FF; idx += 256) {
        const int k = idx >> 5, f = idx & 31;
        const int t = t0 + f;
        float vr = 0.f, vi = 0.f;
        if (t < TFRAMES) {
            const size_t g = specBase + (size_t)k * TFRAMES + (size_t)t;
            vr = gre[g]; vi = gim[g];
        }
        s_re[k][f] = vr; s_im[k][f] = vi;
    }
    __syncthreads();

    const int ng = tid & 63, fg = tid >> 6, f0 = fg * 8;
    float cphi[4], sphi[4], cc[4], ss[4], acc[4][8];
    #pragma unroll
    for (int j = 0; j < 4; ++j) {
        const int m = ng + 64 * j;
        sincospif((float)(m + 1) * (1.0f / 128.0f), &sphi[j], &cphi[j]);
        cc[j] = 1.f; ss[j] = 0.f;
        #pragma unroll
        for (int f = 0; f < 8; ++f) acc[j][f] = 0.f;
    }
    #pragma unroll 2
    for (int k = 1; k <= 127; ++k) {
        const float4 rl = *(const float4*)&s_re[k][f0];
        const float4 rh = *(const float4*)&s_re[k][f0 + 4];
        const float4 il = *(const float4*)&s_im[k][f0];
        const float4 ih = *(const float4*)&s_im[k][f0 + 4];
        #pragma unroll
        for (int j = 0; j < 4; ++j) {
            const float c2 = cc[j] * cphi[j] - ss[j] * sphi[j];
            const float s2 = ss[j] * cphi[j] + cc[j] * sphi[j];
            cc[j] = c2; ss[j] = s2;
            acc[j][0] += rl.x * c2 + il.x * s2;
            acc[j][1] += rl.y * c2 + il.y * s2;
            acc[j][2] += rl.z * c2 + il.z * s2;
            acc[j][3] += rl.w * c2 + il.w * s2;
            acc[j][4] += rh.x * c2 + ih.x * s2;
            acc[j][5] += rh.y * c2 + ih.y * s2;
            acc[j][6] += rh.z * c2 + ih.z * s2;
            acc[j][7] += rh.w * c2 + ih.w * s2;
        }
    }
    float r0[8], r128[8];
    #pragma unroll
    for (int f = 0; f < 8; ++f) { r0[f] = s_re[0][f0 + f]; r128[f] = s_re[128][f0 + f]; }
    __syncthreads();
    #pragma unroll
    for (int j = 0; j < 4; ++j) {
        const int m = ng + 64 * j;
        const float sgn = (m & 1) ? 1.0f : -1.0f;
        #pragma unroll
        for (int f = 0; f < 8; ++f)
            s_G[f0 + f][m] = (r0[f] + 2.0f * acc[j][f] + sgn * r128[f]) * (1.0f / 256.0f);
    }
    __syncthreads();
    const size_t outBase = (size_t)bc * OUTL;
    const int i0 = q * CHUNK;
    #pragma unroll 1
    for (int r = 0; r < 13; ++r) {
        const int i = i0 + r * 256 + tid;
        if (i < OUTL) {
            const int s = i + SHIFT;
            int tlo = (s - 640) >> 7;  if (tlo < t0) tlo = t0;
            int thi = s >> 7;
            if (thi > t0 + FF - 1) thi = t0 + FF - 1;
            if (thi > TFRAMES - 1) thi = TFRAMES - 1;
            float sum = 0.f;
            for (int t = tlo; t <= thi; ++t) {
                const int jj = s - (t << 7);
                sum += s_lpf[jj] * s_G[t - t0][jj & 255];
            }
            out[outBase + i] = sum * (-32768.0f);
        }
    }
}

extern "C" void kernel_launch(void* const* d_in, const int* in_sizes, int n_in,
                              void* d_out, int out_size, void* d_ws, size_t ws_size,
                              hipStream_t stream)
{
    const float* gre  = (const float*)d_in[0];
    const float* gim  = (const float*)d_in[1];
    const float* glpf = (const float*)d_in[2];
    float* out = (float*)d_out;

    if (ws_size >= (size_t)WBYTES) {
        ushort* wp = (ushort*)d_ws;
        build_w_kernel<<<36, 256, 0, stream>>>(wp);
        dim3 grid(NCHUNK, 16);
        pfb_mfma_kernel<<<grid, 256, 0, stream>>>(gre, gim, glpf, wp, out);
    } else {
        dim3 grid(NCHUNK, 16);
        pfb_fused_kernel<<<grid, 256, 0, stream>>>(gre, gim, glpf, out);
    }
}